// Round 2
// baseline (978.060 us; speedup 1.0000x reference)
//
#include <hip/hip_runtime.h>

#define T_TOK 8192
#define DM    1024
#define DFF   4096
#define NE    8
#define SLOTS_MAX 18432   // 16384 + 8*255 rounded to 256

typedef __attribute__((ext_vector_type(4))) float f32x4;
typedef __attribute__((ext_vector_type(8))) short bf16x8;

__device__ __forceinline__ unsigned short f2bf(float f) {
  unsigned int u = __float_as_uint(f);
  u = (u + 0x7FFFu + ((u >> 16) & 1u)) >> 16;
  return (unsigned short)u;
}
__device__ __forceinline__ float bf2f(unsigned short u) {
  return __uint_as_float(((unsigned)u) << 16);
}

__device__ __forceinline__ void gld_lds16(const void* g, void* l) {
  __builtin_amdgcn_global_load_lds(
      (const __attribute__((address_space(1))) void*)g,
      (__attribute__((address_space(3))) void*)l, 16, 0, 0);
}

__device__ __forceinline__ bf16x8 ldsr(unsigned addr) {
  bf16x8 r;
  asm volatile("ds_read_b128 %0, %1" : "=v"(r) : "v"(addr));
  return r;
}

// ---------- weight transpose + fp32->bf16: W [E][R][C] -> Wt [E][C][R] ----------
__global__ __launch_bounds__(256) void transpose_convert(
    const float* __restrict__ W, unsigned short* __restrict__ Wt, int R, int C)
{
  __shared__ float tile[64][65];
  int e = blockIdx.z;
  const float* We = W + (size_t)e * R * C;
  unsigned short* Wte = Wt + (size_t)e * R * C;
  int c0 = blockIdx.x * 64, r0 = blockIdx.y * 64;
  int tid = threadIdx.x;
  int lr = tid >> 4, lc = (tid & 15) * 4;
#pragma unroll
  for (int i = 0; i < 4; ++i) {
    float4 v = *(const float4*)(We + (size_t)(r0 + i * 16 + lr) * C + c0 + lc);
    tile[i * 16 + lr][lc] = v.x; tile[i * 16 + lr][lc + 1] = v.y;
    tile[i * 16 + lr][lc + 2] = v.z; tile[i * 16 + lr][lc + 3] = v.w;
  }
  __syncthreads();
#pragma unroll
  for (int i = 0; i < 4; ++i) {
    int o = i * 256 + tid;
    int rq = o & 15, cw = o >> 4;      // rq: 16 per col, consecutive tid -> contiguous writes
    ushort4 u;
    u.x = f2bf(tile[rq * 4 + 0][cw]); u.y = f2bf(tile[rq * 4 + 1][cw]);
    u.z = f2bf(tile[rq * 4 + 2][cw]); u.w = f2bf(tile[rq * 4 + 3][cw]);
    *(ushort4*)(Wte + (size_t)(c0 + cw) * R + r0 + rq * 4) = u;
  }
}

// ---------- router: wave per token ----------
__global__ __launch_bounds__(256) void router_kernel(
    const float* __restrict__ x, const float* __restrict__ Wg, const float* __restrict__ bg,
    int* __restrict__ topk_idx, float* __restrict__ topk_w,
    int* __restrict__ cnt_sh, float* __restrict__ P_sh)
{
  __shared__ float wgT[NE * DM];
  for (int i = threadIdx.x; i < NE * DM; i += 256) {
    int d = i >> 3, e = i & 7;
    wgT[e * DM + d] = Wg[i];
  }
  __syncthreads();
  int w = threadIdx.x >> 6, lane = threadIdx.x & 63;
  int sh = blockIdx.x & 63;
  for (int it = 0; it < 4; ++it) {
    int t = (blockIdx.x * 4 + w) * 4 + it;
    float p[NE];
#pragma unroll
    for (int e = 0; e < NE; ++e) p[e] = 0.f;
#pragma unroll
    for (int ps = 0; ps < 4; ++ps) {
      int d0 = ps * 256 + lane * 4;
      float4 xv = *(const float4*)(x + (size_t)t * DM + d0);
#pragma unroll
      for (int e = 0; e < NE; ++e) {
        float4 wv = *(const float4*)(wgT + e * DM + d0);
        p[e] += xv.x * wv.x + xv.y * wv.y + xv.z * wv.z + xv.w * wv.w;
      }
    }
#pragma unroll
    for (int e = 0; e < NE; ++e) {
#pragma unroll
      for (int o = 1; o < 64; o <<= 1) p[e] += __shfl_xor(p[e], o);
      p[e] += bg[e];
    }
    float mx = p[0];
#pragma unroll
    for (int e = 1; e < NE; ++e) mx = fmaxf(mx, p[e]);
    float se = 0.f;
#pragma unroll
    for (int e = 0; e < NE; ++e) { p[e] = expf(p[e] - mx); se += p[e]; }
    float inv = 1.f / se;
#pragma unroll
    for (int e = 0; e < NE; ++e) p[e] *= inv;
    int e0 = 0; float v0 = p[0];
#pragma unroll
    for (int e = 1; e < NE; ++e) if (p[e] > v0) { v0 = p[e]; e0 = e; }
    int e1 = -1; float v1 = -1.f;
#pragma unroll
    for (int e = 0; e < NE; ++e) if (e != e0 && p[e] > v1) { v1 = p[e]; e1 = e; }
    if (lane == 0) {
      topk_idx[t * 2] = e0; topk_idx[t * 2 + 1] = e1;
      topk_w[t * 2] = v0;  topk_w[t * 2 + 1] = v1;
      atomicAdd(&cnt_sh[sh * 8 + e0], 1);
      atomicAdd(&cnt_sh[sh * 8 + e1], 1);
#pragma unroll
      for (int e = 0; e < NE; ++e) atomicAdd(&P_sh[sh * 8 + e], p[e]);
    }
  }
}

// ---------- reduce shadow counts, 256-aligned per-expert offsets ----------
__global__ void offsets_kernel(const int* __restrict__ cnt_sh,
                               int* __restrict__ count, int* __restrict__ expOff)
{
  int e = threadIdx.x;
  if (e < NE) {
    int c = 0;
    for (int i = 0; i < 64; ++i) c += cnt_sh[i * 8 + e];
    count[e] = c;
  }
  __syncthreads();
  if (threadIdx.x == 0) {
    int o = 0;
    for (int q = 0; q < NE; ++q) {
      expOff[q] = o;
      o += ((count[q] + 255) >> 8) << 8;
    }
    expOff[NE] = o;
  }
}

// ---------- gather: wave per (token,k) slot ----------
__global__ __launch_bounds__(256) void gather_kernel(
    const float* __restrict__ x, const int* __restrict__ topk_idx,
    const float* __restrict__ topk_w, const int* __restrict__ expOff,
    int* __restrict__ pos, int* __restrict__ slotOf, float* __restrict__ slot_w,
    unsigned short* __restrict__ Abuf)
{
  int w = threadIdx.x >> 6, lane = threadIdx.x & 63;
  int a = blockIdx.x * 4 + w;        // 0..16383
  int t = a >> 1;
  int e = topk_idx[a];
  int p = 0;
  if (lane == 0) p = atomicAdd(&pos[e], 1);
  p = __shfl(p, 0);
  int slot = expOff[e] + p;
  if (lane == 0) { slotOf[a] = slot; slot_w[slot] = topk_w[a]; }
  const float* xr = x + (size_t)t * DM;
  unsigned short* dst = Abuf + (size_t)slot * DM;
#pragma unroll
  for (int j = 0; j < 4; ++j) {
    int idx = j * 256 + lane * 4;
    float4 v = *(const float4*)(xr + idx);
    ushort4 u;
    u.x = f2bf(v.x); u.y = f2bf(v.y); u.z = f2bf(v.z); u.w = f2bf(v.w);
    *(ushort4*)(dst + idx) = u;
  }
}

// ---------- grouped GEMM, 256x256xBK64, 8 waves, dbuf + counted vmcnt ----------
// EPI 0: Hout = relu(acc+bias) bf16.   EPI 1 (split-K=2): Ybuf[s][slot] = bf16(w*(acc + (s==0)*bias))
template<int KDIM, int EPI>
__global__ __launch_bounds__(512) void moe_gemm(
    const unsigned short* __restrict__ A, const unsigned short* __restrict__ Bt,
    const float* __restrict__ bias, unsigned short* __restrict__ Out,
    const int* __restrict__ expOff, const float* __restrict__ slot_w, int N)
{
  constexpr int KT = (EPI == 0 ? KDIM : KDIM / 2) / 64;
  int e, koff, sp;
  if (EPI == 0) { e = blockIdx.z; koff = 0; sp = 0; }
  else { e = blockIdx.z >> 1; sp = blockIdx.z & 1; koff = sp * (KDIM / 2); }

  int off = expOff[e];
  int pad = expOff[e + 1] - off;

  // bijective XCD swizzle: each XCD gets a contiguous n-chunk (m fastest)
  int nx = N >> 8;                       // n-tiles (16 or 4)
  int b = blockIdx.x + blockIdx.y * nx;  // hw linear order within z-slice
  int cpx = nx * 8;                      // (nx*64)/8
  int wg = (b & 7) * cpx + (b >> 3);
  int ntile = wg >> 6, mt = wg & 63;
  if (mt * 256 >= pad) return;
  int m0 = off + mt * 256, n0 = ntile * 256;

  __shared__ __align__(16) char lds[131072];   // 2 bufs x (A 32KB + B 32KB)

  const int lane = threadIdx.x & 63, w = threadIdx.x >> 6;
  const int wr = w >> 2, wc = w & 3;

  // staging: chunk ch (16B) holds global (row ch/8, col-slot (ch&7)^(row&7)) -> linear LDS
  const int sxor = 8 * ((lane & 7) ^ (lane >> 3));
  const unsigned short* Ab = A + (size_t)(m0 + (lane >> 3)) * KDIM + koff + sxor;
  const unsigned short* Bb = Bt + (size_t)e * N * KDIM + (size_t)(n0 + (lane >> 3)) * KDIM + koff + sxor;

  // read-side swizzled offsets
  unsigned lbase = (unsigned)(size_t)(__attribute__((address_space(3))) char*)lds;
  const unsigned arow = (unsigned)((wr * 128 + (lane & 15)) * 128);
  const unsigned brow = 32768u + (unsigned)((wc * 64 + (lane & 15)) * 128);
  const unsigned xo0 = 16u * (unsigned)(((lane >> 4)) ^ (lane & 7));
  const unsigned xo1 = 16u * (unsigned)((4 + (lane >> 4)) ^ (lane & 7));

  f32x4 acc[8][4] = {};
  bf16x8 af[4][2];

#define STAGE(KT_, BUF_)                                                     \
  {                                                                          \
    int k0_ = (KT_) * 64;                                                    \
    char* la_ = lds + (BUF_) * 65536;                                        \
    char* lb_ = la_ + 32768;                                                 \
    _Pragma("unroll") for (int c_ = 0; c_ < 4; ++c_) {                       \
      int gg_ = c_ * 8 + w;                                                  \
      gld_lds16(Ab + (size_t)gg_ * 8 * KDIM + k0_, la_ + gg_ * 1024);        \
      gld_lds16(Bb + (size_t)gg_ * 8 * KDIM + k0_, lb_ + gg_ * 1024);        \
    }                                                                        \
  }

#define PHASE(MH, NH, READA)                                                 \
  {                                                                          \
    if (READA) {                                                             \
      _Pragma("unroll") for (int mi = 0; mi < 4; ++mi) {                     \
        af[mi][0] = ldsr(bo + arow + ((MH) * 4 + mi) * 2048u + xo0);         \
        af[mi][1] = ldsr(bo + arow + ((MH) * 4 + mi) * 2048u + xo1);         \
      }                                                                      \
    }                                                                        \
    bf16x8 bq[2][2];                                                         \
    _Pragma("unroll") for (int ni = 0; ni < 2; ++ni) {                       \
      bq[ni][0] = ldsr(bo + brow + ((NH) * 2 + ni) * 2048u + xo0);           \
      bq[ni][1] = ldsr(bo + brow + ((NH) * 2 + ni) * 2048u + xo1);           \
    }                                                                        \
    asm volatile("s_barrier" ::: "memory");                                  \
    asm volatile("s_waitcnt lgkmcnt(0)" ::: "memory");                       \
    __builtin_amdgcn_sched_barrier(0);                                       \
    __builtin_amdgcn_s_setprio(1);                                           \
    _Pragma("unroll") for (int mi = 0; mi < 4; ++mi)                         \
      _Pragma("unroll") for (int ni = 0; ni < 2; ++ni) {                     \
        acc[(MH) * 4 + mi][(NH) * 2 + ni] =                                  \
            __builtin_amdgcn_mfma_f32_16x16x32_bf16(                         \
                af[mi][0], bq[ni][0], acc[(MH) * 4 + mi][(NH) * 2 + ni], 0, 0, 0); \
        acc[(MH) * 4 + mi][(NH) * 2 + ni] =                                  \
            __builtin_amdgcn_mfma_f32_16x16x32_bf16(                         \
                af[mi][1], bq[ni][1], acc[(MH) * 4 + mi][(NH) * 2 + ni], 0, 0, 0); \
      }                                                                      \
    __builtin_amdgcn_s_setprio(0);                                           \
    asm volatile("s_barrier" ::: "memory");                                  \
  }

  // prologue: K-tiles 0,1 in flight; wait tile 0
  STAGE(0, 0)
  STAGE(1, 1)
  asm volatile("s_waitcnt vmcnt(8)" ::: "memory");
  asm volatile("s_barrier" ::: "memory");

#pragma unroll 1
  for (int kt = 0; kt < KT; ++kt) {
    unsigned bo = lbase + (unsigned)((kt & 1) * 65536);
    PHASE(0, 0, 1)
    PHASE(0, 1, 0)
    PHASE(1, 0, 1)
    PHASE(1, 1, 0)
    // all waves past their reads of buf[kt&1]; refill it with K-tile kt+2
    if (kt + 2 < KT) {
      STAGE(kt + 2, kt & 1)
      asm volatile("s_waitcnt vmcnt(8)" ::: "memory");   // kt+1 resident
      asm volatile("s_barrier" ::: "memory");
    } else if (kt + 1 < KT) {
      asm volatile("s_waitcnt vmcnt(0)" ::: "memory");
      asm volatile("s_barrier" ::: "memory");
    }
  }
#undef STAGE
#undef PHASE

  int cn = lane & 15;
  int r4 = (lane >> 4) * 4;
  if (EPI == 0) {
#pragma unroll
    for (int ni = 0; ni < 4; ++ni) {
      int col = n0 + wc * 64 + ni * 16 + cn;
      float bv = bias[e * N + col];
#pragma unroll
      for (int mi = 0; mi < 8; ++mi) {
        int row = m0 + wr * 128 + mi * 16 + r4;
#pragma unroll
        for (int j = 0; j < 4; ++j) {
          float v = acc[mi][ni][j] + bv;
          Out[(size_t)(row + j) * N + col] = f2bf(v > 0.f ? v : 0.f);
        }
      }
    }
  } else {
    unsigned short* Yw = Out + (size_t)sp * SLOTS_MAX * DM;
    float bv[4];
#pragma unroll
    for (int ni = 0; ni < 4; ++ni)
      bv[ni] = (sp == 0) ? bias[e * N + n0 + wc * 64 + ni * 16 + cn] : 0.f;
#pragma unroll
    for (int mi = 0; mi < 8; ++mi) {
      int rbase = m0 + wr * 128 + mi * 16 + r4;
#pragma unroll
      for (int j = 0; j < 4; ++j) {
        int slot = rbase + j;
        float wgt = slot_w[slot];
#pragma unroll
        for (int ni = 0; ni < 4; ++ni) {
          int col = n0 + wc * 64 + ni * 16 + cn;
          Yw[(size_t)slot * DM + col] = f2bf(wgt * (acc[mi][ni][j] + bv[ni]));
        }
      }
    }
  }
}

// ---------- residual + LayerNorm (sums 4 bf16 partial rows per token) ----------
__global__ __launch_bounds__(256) void ln_kernel(
    const float* __restrict__ x, const unsigned short* __restrict__ Ybuf,
    const int* __restrict__ slotOf,
    const float* __restrict__ gamma, const float* __restrict__ beta,
    float* __restrict__ out)
{
  int t = blockIdx.x;
  int s0 = slotOf[2 * t], s1 = slotOf[2 * t + 1];
  const unsigned short* y00 = Ybuf + (size_t)s0 * DM;
  const unsigned short* y01 = Ybuf + (size_t)SLOTS_MAX * DM + (size_t)s0 * DM;
  const unsigned short* y10 = Ybuf + (size_t)s1 * DM;
  const unsigned short* y11 = Ybuf + (size_t)SLOTS_MAX * DM + (size_t)s1 * DM;
  int c = threadIdx.x * 4;
  float4 xv = *(const float4*)(x + (size_t)t * DM + c);
  ushort4 a0 = *(const ushort4*)(y00 + c);
  ushort4 a1 = *(const ushort4*)(y01 + c);
  ushort4 a2 = *(const ushort4*)(y10 + c);
  ushort4 a3 = *(const ushort4*)(y11 + c);
  float z[4];
  z[0] = xv.x + bf2f(a0.x) + bf2f(a1.x) + bf2f(a2.x) + bf2f(a3.x);
  z[1] = xv.y + bf2f(a0.y) + bf2f(a1.y) + bf2f(a2.y) + bf2f(a3.y);
  z[2] = xv.z + bf2f(a0.z) + bf2f(a1.z) + bf2f(a2.z) + bf2f(a3.z);
  z[3] = xv.w + bf2f(a0.w) + bf2f(a1.w) + bf2f(a2.w) + bf2f(a3.w);
  float s = z[0] + z[1] + z[2] + z[3];
  float s2 = z[0]*z[0] + z[1]*z[1] + z[2]*z[2] + z[3]*z[3];
#pragma unroll
  for (int o = 1; o < 64; o <<= 1) { s += __shfl_xor(s, o); s2 += __shfl_xor(s2, o); }
  __shared__ float ls[8];
  int w = threadIdx.x >> 6, lane = threadIdx.x & 63;
  if (lane == 0) { ls[w] = s; ls[4 + w] = s2; }
  __syncthreads();
  s = ls[0] + ls[1] + ls[2] + ls[3];
  s2 = ls[4] + ls[5] + ls[6] + ls[7];
  float mu = s * (1.f / DM);
  float var = s2 * (1.f / DM) - mu * mu;
  float rstd = rsqrtf(var + 1e-5f);
  float4 gv = *(const float4*)(gamma + c);
  float4 bv = *(const float4*)(beta + c);
  float4 ov;
  ov.x = (z[0] - mu) * rstd * gv.x + bv.x;
  ov.y = (z[1] - mu) * rstd * gv.y + bv.y;
  ov.z = (z[2] - mu) * rstd * gv.z + bv.z;
  ov.w = (z[3] - mu) * rstd * gv.w + bv.w;
  *(float4*)(out + (size_t)t * DM + c) = ov;
}

// ---------- aux loss ----------
__global__ void aux_kernel(const float* __restrict__ P_sh,
                           const int* __restrict__ count, float* __restrict__ out_aux)
{
  if (threadIdx.x == 0) {
    float aux = 0.f;
    for (int e = 0; e < NE; ++e) {
      float P = 0.f;
      for (int i = 0; i < 64; ++i) P += P_sh[i * 8 + e];
      P *= (1.f / T_TOK);
      float f = count[e] * (1.f / (T_TOK * 2));
      aux += f * P;
    }
    out_aux[0] = (float)NE * aux;
  }
}

extern "C" void kernel_launch(void* const* d_in, const int* in_sizes, int n_in,
                              void* d_out, int out_size, void* d_ws, size_t ws_size,
                              hipStream_t stream)
{
  (void)in_sizes; (void)n_in; (void)out_size; (void)ws_size;
  const float* x     = (const float*)d_in[0];
  const float* Wg    = (const float*)d_in[1];
  const float* bg    = (const float*)d_in[2];
  const float* W1    = (const float*)d_in[3];
  const float* b1    = (const float*)d_in[4];
  const float* W2    = (const float*)d_in[5];
  const float* b2    = (const float*)d_in[6];
  const float* gamma = (const float*)d_in[7];
  const float* beta  = (const float*)d_in[8];
  float* out = (float*)d_out;

  char* ws = (char*)d_ws;
  size_t off = 0;
  auto alloc = [&](size_t bytes) -> void* {
    void* p = ws + off;
    off += (bytes + 255) & ~(size_t)255;
    return p;
  };
  int*   cnt_sh   = (int*)alloc(64 * 8 * 4);
  float* P_sh     = (float*)alloc(64 * 8 * 4);
  int*   count    = (int*)alloc(8 * 4);
  int*   pos      = (int*)alloc(8 * 4);
  size_t meta_end = off;
  int*   expOff   = (int*)alloc(9 * 4);
  int*   topk_idx = (int*)alloc(16384 * 4);
  float* topk_w   = (float*)alloc(16384 * 4);
  int*   slotOf   = (int*)alloc(16384 * 4);
  float* slot_w   = (float*)alloc((size_t)SLOTS_MAX * 4);
  unsigned short* Hbuf = (unsigned short*)alloc((size_t)SLOTS_MAX * DFF * 2);
  unsigned short* W2t  = (unsigned short*)alloc((size_t)NE * DM * DFF * 2);
  unsigned short* Abuf = (unsigned short*)alloc((size_t)SLOTS_MAX * DM * 2);
  // W1t region doubles as Ybuf (2 split-K partial buffers); W1t dead after GEMM1
  unsigned short* W1t  = (unsigned short*)alloc((size_t)2 * SLOTS_MAX * DM * 2);
  unsigned short* Ybuf = W1t;

  hipMemsetAsync(d_ws, 0, meta_end, stream);

  transpose_convert<<<dim3(DFF / 64, DM / 64, NE), 256, 0, stream>>>(W1, W1t, DM, DFF);
  transpose_convert<<<dim3(DM / 64, DFF / 64, NE), 256, 0, stream>>>(W2, W2t, DFF, DM);
  router_kernel<<<512, 256, 0, stream>>>(x, Wg, bg, topk_idx, topk_w, cnt_sh, P_sh);
  offsets_kernel<<<1, 64, 0, stream>>>(cnt_sh, count, expOff);
  gather_kernel<<<4096, 256, 0, stream>>>(x, topk_idx, topk_w, expOff, pos, slotOf, slot_w, Abuf);
  moe_gemm<DM, 0><<<dim3(16, 64, 8), 512, 0, stream>>>(
      Abuf, W1t, b1, Hbuf, expOff, slot_w, DFF);
  moe_gemm<DFF, 1><<<dim3(4, 64, 16), 512, 0, stream>>>(
      Hbuf, W2t, b2, Ybuf, expOff, slot_w, DM);
  ln_kernel<<<T_TOK, 256, 0, stream>>>(x, Ybuf, slotOf, gamma, beta, out);
  aux_kernel<<<1, 64, 0, stream>>>(P_sh, count, out + (size_t)T_TOK * DM);
}

// Round 3
// 836.767 us; speedup vs baseline: 1.1689x; 1.1689x over previous
//
#include <hip/hip_runtime.h>

#define T_TOK 8192
#define DM    1024
#define DFF   4096
#define NE    8
#define SLOTS_MAX 18432   // 16384 + 8*255 rounded to 256
#define MT_MAX 16         // max m-tiles of 256 per expert (supports 4096 rows/expert)

typedef __attribute__((ext_vector_type(4))) float f32x4;
typedef __attribute__((ext_vector_type(8))) short bf16x8;

__device__ __forceinline__ unsigned short f2bf(float f) {
  unsigned int u = __float_as_uint(f);
  u = (u + 0x7FFFu + ((u >> 16) & 1u)) >> 16;
  return (unsigned short)u;
}
__device__ __forceinline__ float bf2f(unsigned short u) {
  return __uint_as_float(((unsigned)u) << 16);
}

__device__ __forceinline__ void gld_lds16(const void* g, void* l) {
  __builtin_amdgcn_global_load_lds(
      (const __attribute__((address_space(1))) void*)g,
      (__attribute__((address_space(3))) void*)l, 16, 0, 0);
}

__device__ __forceinline__ bf16x8 ldsr(unsigned addr) {
  bf16x8 r;
  asm volatile("ds_read_b128 %0, %1" : "=v"(r) : "v"(addr));
  return r;
}

// ---------- weight transpose + fp32->bf16: W [E][R][C] -> Wt [E][C][R] ----------
__global__ __launch_bounds__(256) void transpose_convert(
    const float* __restrict__ W, unsigned short* __restrict__ Wt, int R, int C)
{
  __shared__ float tile[64][65];
  int e = blockIdx.z;
  const float* We = W + (size_t)e * R * C;
  unsigned short* Wte = Wt + (size_t)e * R * C;
  int c0 = blockIdx.x * 64, r0 = blockIdx.y * 64;
  int tid = threadIdx.x;
  int lr = tid >> 4, lc = (tid & 15) * 4;
#pragma unroll
  for (int i = 0; i < 4; ++i) {
    float4 v = *(const float4*)(We + (size_t)(r0 + i * 16 + lr) * C + c0 + lc);
    tile[i * 16 + lr][lc] = v.x; tile[i * 16 + lr][lc + 1] = v.y;
    tile[i * 16 + lr][lc + 2] = v.z; tile[i * 16 + lr][lc + 3] = v.w;
  }
  __syncthreads();
#pragma unroll
  for (int i = 0; i < 4; ++i) {
    int o = i * 256 + tid;
    int rq = o & 15, cw = o >> 4;
    ushort4 u;
    u.x = f2bf(tile[rq * 4 + 0][cw]); u.y = f2bf(tile[rq * 4 + 1][cw]);
    u.z = f2bf(tile[rq * 4 + 2][cw]); u.w = f2bf(tile[rq * 4 + 3][cw]);
    *(ushort4*)(Wte + (size_t)(c0 + cw) * R + r0 + rq * 4) = u;
  }
}

// ---------- router: wave per token ----------
__global__ __launch_bounds__(256) void router_kernel(
    const float* __restrict__ x, const float* __restrict__ Wg, const float* __restrict__ bg,
    int* __restrict__ topk_idx, float* __restrict__ topk_w,
    int* __restrict__ cnt_sh, float* __restrict__ P_sh)
{
  __shared__ float wgT[NE * DM];
  for (int i = threadIdx.x; i < NE * DM; i += 256) {
    int d = i >> 3, e = i & 7;
    wgT[e * DM + d] = Wg[i];
  }
  __syncthreads();
  int w = threadIdx.x >> 6, lane = threadIdx.x & 63;
  int sh = blockIdx.x & 63;
  for (int it = 0; it < 4; ++it) {
    int t = (blockIdx.x * 4 + w) * 4 + it;
    float p[NE];
#pragma unroll
    for (int e = 0; e < NE; ++e) p[e] = 0.f;
#pragma unroll
    for (int ps = 0; ps < 4; ++ps) {
      int d0 = ps * 256 + lane * 4;
      float4 xv = *(const float4*)(x + (size_t)t * DM + d0);
#pragma unroll
      for (int e = 0; e < NE; ++e) {
        float4 wv = *(const float4*)(wgT + e * DM + d0);
        p[e] += xv.x * wv.x + xv.y * wv.y + xv.z * wv.z + xv.w * wv.w;
      }
    }
#pragma unroll
    for (int e = 0; e < NE; ++e) {
#pragma unroll
      for (int o = 1; o < 64; o <<= 1) p[e] += __shfl_xor(p[e], o);
      p[e] += bg[e];
    }
    float mx = p[0];
#pragma unroll
    for (int e = 1; e < NE; ++e) mx = fmaxf(mx, p[e]);
    float se = 0.f;
#pragma unroll
    for (int e = 0; e < NE; ++e) { p[e] = expf(p[e] - mx); se += p[e]; }
    float inv = 1.f / se;
#pragma unroll
    for (int e = 0; e < NE; ++e) p[e] *= inv;
    int e0 = 0; float v0 = p[0];
#pragma unroll
    for (int e = 1; e < NE; ++e) if (p[e] > v0) { v0 = p[e]; e0 = e; }
    int e1 = -1; float v1 = -1.f;
#pragma unroll
    for (int e = 0; e < NE; ++e) if (e != e0 && p[e] > v1) { v1 = p[e]; e1 = e; }
    if (lane == 0) {
      topk_idx[t * 2] = e0; topk_idx[t * 2 + 1] = e1;
      topk_w[t * 2] = v0;  topk_w[t * 2 + 1] = v1;
      atomicAdd(&cnt_sh[sh * 8 + e0], 1);
      atomicAdd(&cnt_sh[sh * 8 + e1], 1);
#pragma unroll
      for (int e = 0; e < NE; ++e) atomicAdd(&P_sh[sh * 8 + e], p[e]);
    }
  }
}

// ---------- reduce shadow counts, 256-aligned per-expert offsets ----------
__global__ void offsets_kernel(const int* __restrict__ cnt_sh,
                               int* __restrict__ count, int* __restrict__ expOff)
{
  int e = threadIdx.x;
  if (e < NE) {
    int c = 0;
    for (int i = 0; i < 64; ++i) c += cnt_sh[i * 8 + e];
    count[e] = c;
  }
  __syncthreads();
  if (threadIdx.x == 0) {
    int o = 0;
    for (int q = 0; q < NE; ++q) {
      expOff[q] = o;
      o += ((count[q] + 255) >> 8) << 8;
    }
    expOff[NE] = o;
  }
}

// ---------- gather: wave per (token,k) slot ----------
__global__ __launch_bounds__(256) void gather_kernel(
    const float* __restrict__ x, const int* __restrict__ topk_idx,
    const float* __restrict__ topk_w, const int* __restrict__ expOff,
    int* __restrict__ pos, int* __restrict__ slotOf, float* __restrict__ slot_w,
    unsigned short* __restrict__ Abuf)
{
  int w = threadIdx.x >> 6, lane = threadIdx.x & 63;
  int a = blockIdx.x * 4 + w;
  int t = a >> 1;
  int e = topk_idx[a];
  int p = 0;
  if (lane == 0) p = atomicAdd(&pos[e], 1);
  p = __shfl(p, 0);
  int slot = expOff[e] + p;
  if (lane == 0) { slotOf[a] = slot; slot_w[slot] = topk_w[a]; }
  const float* xr = x + (size_t)t * DM;
  unsigned short* dst = Abuf + (size_t)slot * DM;
#pragma unroll
  for (int j = 0; j < 4; ++j) {
    int idx = j * 256 + lane * 4;
    float4 v = *(const float4*)(xr + idx);
    ushort4 u;
    u.x = f2bf(v.x); u.y = f2bf(v.y); u.z = f2bf(v.z); u.w = f2bf(v.w);
    *(ushort4*)(dst + idx) = u;
  }
}

// ---------- grouped GEMM 256x256xBK64, 8 waves, reg-pipelined phases ----------
// EPI 0: Hout = relu(acc+bias) bf16.   EPI 1 (split-K=2): Ybuf[s][slot] = bf16(w*(acc+(s==0)*bias))
template<int KDIM, int EPI>
__global__ __launch_bounds__(512, 2) void moe_gemm(
    const unsigned short* __restrict__ A, const unsigned short* __restrict__ Bt,
    const float* __restrict__ bias, unsigned short* __restrict__ Out,
    const int* __restrict__ expOff, const float* __restrict__ slot_w, int N)
{
  constexpr int KT = (EPI == 0 ? KDIM : KDIM / 2) / 64;
  int e, koff, sp;
  if (EPI == 0) { e = blockIdx.z; koff = 0; sp = 0; }
  else { e = blockIdx.z >> 1; sp = blockIdx.z & 1; koff = sp * (KDIM / 2); }

  int off = expOff[e];
  int pad = expOff[e + 1] - off;

  // bijective XCD swizzle within z-slice: each XCD gets contiguous n-chunk
  int nx = N >> 8;
  int b = blockIdx.x + blockIdx.y * nx;      // [0, nx*MT_MAX)
  int cpx = nx * MT_MAX / 8;
  int wg = (b & 7) * cpx + (b >> 3);
  int ntile = wg / MT_MAX, mt = wg % MT_MAX;
  if (mt * 256 >= pad) return;
  int m0 = off + mt * 256, n0 = ntile * 256;

  __shared__ __align__(16) char lds[131072];   // 2 bufs x (A 32KB + B 32KB)

  const int lane = threadIdx.x & 63, w = threadIdx.x >> 6;
  const int wr = w >> 2, wc = w & 3;

  // staging: per 16B chunk, global col-slot = (slot ^ (row&7)); LDS stays linear
  const int sxor = 8 * ((lane & 7) ^ (lane >> 3));
  const unsigned short* Ab = A + (size_t)(m0 + (lane >> 3)) * KDIM + koff + sxor;
  const unsigned short* Bb = Bt + (size_t)e * N * KDIM + (size_t)(n0 + (lane >> 3)) * KDIM + koff + sxor;

  unsigned lbase = (unsigned)(size_t)(__attribute__((address_space(3))) char*)lds;
  const unsigned arow = (unsigned)((wr * 128 + (lane & 15)) * 128);
  const unsigned brow = 32768u + (unsigned)((wc * 64 + (lane & 15)) * 128);
  const unsigned xo0 = 16u * (unsigned)(((lane >> 4)) ^ (lane & 7));
  const unsigned xo1 = 16u * (unsigned)((4 + (lane >> 4)) ^ (lane & 7));

  f32x4 acc[8][4] = {};
  bf16x8 A0[4], A1[4], B0[4], B1[4];

#define STAGE(KT_, BUF_)                                                     \
  {                                                                          \
    int k0_ = (KT_) * 64;                                                    \
    char* la_ = lds + (BUF_) * 65536;                                        \
    char* lb_ = la_ + 32768;                                                 \
    _Pragma("unroll") for (int c_ = 0; c_ < 4; ++c_) {                       \
      int gg_ = c_ * 8 + w;                                                  \
      gld_lds16(Ab + (size_t)gg_ * 8 * KDIM + k0_, la_ + gg_ * 1024);        \
      gld_lds16(Bb + (size_t)gg_ * 8 * KDIM + k0_, lb_ + gg_ * 1024);        \
    }                                                                        \
  }

#define RD_A(DST, BO_, MH, XO_)                                              \
  { _Pragma("unroll") for (int mi = 0; mi < 4; ++mi)                         \
      DST[mi] = ldsr((BO_) + arow + (MH) * 8192u + mi * 2048u + (XO_)); }

#define RD_B(DST, BO_, XO_)                                                  \
  { _Pragma("unroll") for (int ni = 0; ni < 4; ++ni)                         \
      DST[ni] = ldsr((BO_) + brow + ni * 2048u + (XO_)); }

#define WAITL(N_)                                                            \
  { asm volatile("s_waitcnt lgkmcnt(" #N_ ")" ::: "memory");                 \
    __builtin_amdgcn_sched_barrier(0); }

#define MM(MH, AS, BS)                                                       \
  { __builtin_amdgcn_s_setprio(1);                                           \
    _Pragma("unroll") for (int mi = 0; mi < 4; ++mi)                         \
      _Pragma("unroll") for (int ni = 0; ni < 4; ++ni)                       \
        acc[(MH) * 4 + mi][ni] = __builtin_amdgcn_mfma_f32_16x16x32_bf16(    \
            AS[mi], BS[ni], acc[(MH) * 4 + mi][ni], 0, 0, 0);                \
    __builtin_amdgcn_s_setprio(0); }

  // prologue: tile 0 resident, pre-read phase-0 operands
  STAGE(0, 0)
  asm volatile("s_waitcnt vmcnt(0)" ::: "memory");
  __builtin_amdgcn_s_barrier();
  RD_A(A0, lbase, 0, xo0)
  RD_B(B0, lbase, xo0)

#pragma unroll 1
  for (int kt = 0; kt < KT - 1; ++kt) {
    unsigned bo = lbase + (unsigned)((kt & 1) * 65536);
    unsigned bo2 = bo ^ 65536u;
    // i0: stage next tile; read (k0,M1); compute (k0,M0)
    STAGE(kt + 1, (kt + 1) & 1)
    RD_A(A1, bo, 1, xo0)
    WAITL(4)
    MM(0, A0, B0)
    // i1: read (k1,M0)+B(k1); compute (k0,M1)
    RD_A(A0, bo, 0, xo1)
    RD_B(B1, bo, xo1)
    WAITL(8)
    MM(1, A1, B0)
    // i2: read (k1,M1); compute (k1,M0); then make next buffer resident
    RD_A(A1, bo, 1, xo1)
    WAITL(4)
    MM(0, A0, B1)
    asm volatile("s_waitcnt vmcnt(0)" ::: "memory");
    __builtin_amdgcn_s_barrier();          // next tile resident for ALL waves
    // i3: pre-read next tile's (k0,M0)+B(k0); compute (k1,M1)
    RD_A(A0, bo2, 0, xo0)
    RD_B(B0, bo2, xo0)
    WAITL(8)
    MM(1, A1, B1)
    __builtin_amdgcn_s_barrier();          // cur buffer free for refill
  }
  // peeled last tile
  {
    unsigned bo = lbase + (unsigned)(((KT - 1) & 1) * 65536);
    RD_A(A1, bo, 1, xo0)
    WAITL(4)
    MM(0, A0, B0)
    RD_A(A0, bo, 0, xo1)
    RD_B(B1, bo, xo1)
    WAITL(8)
    MM(1, A1, B0)
    RD_A(A1, bo, 1, xo1)
    WAITL(4)
    MM(0, A0, B1)
    WAITL(0)
    MM(1, A1, B1)
  }
#undef STAGE
#undef RD_A
#undef RD_B
#undef WAITL
#undef MM

  int cn = lane & 15;
  int r4 = (lane >> 4) * 4;
  if (EPI == 0) {
#pragma unroll
    for (int ni = 0; ni < 4; ++ni) {
      int col = n0 + wc * 64 + ni * 16 + cn;
      float bv = bias[e * N + col];
#pragma unroll
      for (int mi = 0; mi < 8; ++mi) {
        int row = m0 + wr * 128 + mi * 16 + r4;
#pragma unroll
        for (int j = 0; j < 4; ++j) {
          float v = acc[mi][ni][j] + bv;
          Out[(size_t)(row + j) * N + col] = f2bf(v > 0.f ? v : 0.f);
        }
      }
    }
  } else {
    unsigned short* Yw = Out + (size_t)sp * SLOTS_MAX * DM;
    float bv[4];
#pragma unroll
    for (int ni = 0; ni < 4; ++ni)
      bv[ni] = (sp == 0) ? bias[e * N + n0 + wc * 64 + ni * 16 + cn] : 0.f;
#pragma unroll
    for (int mi = 0; mi < 8; ++mi) {
      int rbase = m0 + wr * 128 + mi * 16 + r4;
#pragma unroll
      for (int j = 0; j < 4; ++j) {
        int slot = rbase + j;
        float wgt = slot_w[slot];
#pragma unroll
        for (int ni = 0; ni < 4; ++ni) {
          int col = n0 + wc * 64 + ni * 16 + cn;
          Yw[(size_t)slot * DM + col] = f2bf(wgt * (acc[mi][ni][j] + bv[ni]));
        }
      }
    }
  }
}

// ---------- residual + LayerNorm (sums 4 bf16 partial rows per token) ----------
__global__ __launch_bounds__(256) void ln_kernel(
    const float* __restrict__ x, const unsigned short* __restrict__ Ybuf,
    const int* __restrict__ slotOf,
    const float* __restrict__ gamma, const float* __restrict__ beta,
    float* __restrict__ out)
{
  int t = blockIdx.x;
  int s0 = slotOf[2 * t], s1 = slotOf[2 * t + 1];
  const unsigned short* y00 = Ybuf + (size_t)s0 * DM;
  const unsigned short* y01 = Ybuf + (size_t)SLOTS_MAX * DM + (size_t)s0 * DM;
  const unsigned short* y10 = Ybuf + (size_t)s1 * DM;
  const unsigned short* y11 = Ybuf + (size_t)SLOTS_MAX * DM + (size_t)s1 * DM;
  int c = threadIdx.x * 4;
  float4 xv = *(const float4*)(x + (size_t)t * DM + c);
  ushort4 a0 = *(const ushort4*)(y00 + c);
  ushort4 a1 = *(const ushort4*)(y01 + c);
  ushort4 a2 = *(const ushort4*)(y10 + c);
  ushort4 a3 = *(const ushort4*)(y11 + c);
  float z[4];
  z[0] = xv.x + bf2f(a0.x) + bf2f(a1.x) + bf2f(a2.x) + bf2f(a3.x);
  z[1] = xv.y + bf2f(a0.y) + bf2f(a1.y) + bf2f(a2.y) + bf2f(a3.y);
  z[2] = xv.z + bf2f(a0.z) + bf2f(a1.z) + bf2f(a2.z) + bf2f(a3.z);
  z[3] = xv.w + bf2f(a0.w) + bf2f(a1.w) + bf2f(a2.w) + bf2f(a3.w);
  float s = z[0] + z[1] + z[2] + z[3];
  float s2 = z[0]*z[0] + z[1]*z[1] + z[2]*z[2] + z[3]*z[3];
#pragma unroll
  for (int o = 1; o < 64; o <<= 1) { s += __shfl_xor(s, o); s2 += __shfl_xor(s2, o); }
  __shared__ float ls[8];
  int w = threadIdx.x >> 6, lane = threadIdx.x & 63;
  if (lane == 0) { ls[w] = s; ls[4 + w] = s2; }
  __syncthreads();
  s = ls[0] + ls[1] + ls[2] + ls[3];
  s2 = ls[4] + ls[5] + ls[6] + ls[7];
  float mu = s * (1.f / DM);
  float var = s2 * (1.f / DM) - mu * mu;
  float rstd = rsqrtf(var + 1e-5f);
  float4 gv = *(const float4*)(gamma + c);
  float4 bv = *(const float4*)(beta + c);
  float4 ov;
  ov.x = (z[0] - mu) * rstd * gv.x + bv.x;
  ov.y = (z[1] - mu) * rstd * gv.y + bv.y;
  ov.z = (z[2] - mu) * rstd * gv.z + bv.z;
  ov.w = (z[3] - mu) * rstd * gv.w + bv.w;
  *(float4*)(out + (size_t)t * DM + c) = ov;
}

// ---------- aux loss ----------
__global__ void aux_kernel(const float* __restrict__ P_sh,
                           const int* __restrict__ count, float* __restrict__ out_aux)
{
  if (threadIdx.x == 0) {
    float aux = 0.f;
    for (int e = 0; e < NE; ++e) {
      float P = 0.f;
      for (int i = 0; i < 64; ++i) P += P_sh[i * 8 + e];
      P *= (1.f / T_TOK);
      float f = count[e] * (1.f / (T_TOK * 2));
      aux += f * P;
    }
    out_aux[0] = (float)NE * aux;
  }
}

extern "C" void kernel_launch(void* const* d_in, const int* in_sizes, int n_in,
                              void* d_out, int out_size, void* d_ws, size_t ws_size,
                              hipStream_t stream)
{
  (void)in_sizes; (void)n_in; (void)out_size; (void)ws_size;
  const float* x     = (const float*)d_in[0];
  const float* Wg    = (const float*)d_in[1];
  const float* bg    = (const float*)d_in[2];
  const float* W1    = (const float*)d_in[3];
  const float* b1    = (const float*)d_in[4];
  const float* W2    = (const float*)d_in[5];
  const float* b2    = (const float*)d_in[6];
  const float* gamma = (const float*)d_in[7];
  const float* beta  = (const float*)d_in[8];
  float* out = (float*)d_out;

  char* ws = (char*)d_ws;
  size_t off = 0;
  auto alloc = [&](size_t bytes) -> void* {
    void* p = ws + off;
    off += (bytes + 255) & ~(size_t)255;
    return p;
  };
  int*   cnt_sh   = (int*)alloc(64 * 8 * 4);
  float* P_sh     = (float*)alloc(64 * 8 * 4);
  int*   count    = (int*)alloc(8 * 4);
  int*   pos      = (int*)alloc(8 * 4);
  size_t meta_end = off;
  int*   expOff   = (int*)alloc(9 * 4);
  int*   topk_idx = (int*)alloc(16384 * 4);
  float* topk_w   = (float*)alloc(16384 * 4);
  int*   slotOf   = (int*)alloc(16384 * 4);
  float* slot_w   = (float*)alloc((size_t)SLOTS_MAX * 4);
  unsigned short* Hbuf = (unsigned short*)alloc((size_t)SLOTS_MAX * DFF * 2);
  unsigned short* W2t  = (unsigned short*)alloc((size_t)NE * DM * DFF * 2);
  unsigned short* Abuf = (unsigned short*)alloc((size_t)SLOTS_MAX * DM * 2);
  // W1t region doubles as Ybuf (2 split-K partial buffers); W1t dead after GEMM1
  unsigned short* W1t  = (unsigned short*)alloc((size_t)2 * SLOTS_MAX * DM * 2);
  unsigned short* Ybuf = W1t;

  hipMemsetAsync(d_ws, 0, meta_end, stream);

  transpose_convert<<<dim3(DFF / 64, DM / 64, NE), 256, 0, stream>>>(W1, W1t, DM, DFF);
  transpose_convert<<<dim3(DM / 64, DFF / 64, NE), 256, 0, stream>>>(W2, W2t, DFF, DM);
  router_kernel<<<512, 256, 0, stream>>>(x, Wg, bg, topk_idx, topk_w, cnt_sh, P_sh);
  offsets_kernel<<<1, 64, 0, stream>>>(cnt_sh, count, expOff);
  gather_kernel<<<4096, 256, 0, stream>>>(x, topk_idx, topk_w, expOff, pos, slotOf, slot_w, Abuf);
  moe_gemm<DM, 0><<<dim3(16, MT_MAX, 8), 512, 0, stream>>>(
      Abuf, W1t, b1, Hbuf, expOff, slot_w, DFF);
  moe_gemm<DFF, 1><<<dim3(4, MT_MAX, 16), 512, 0, stream>>>(
      Hbuf, W2t, b2, Ybuf, expOff, slot_w, DM);
  ln_kernel<<<T_TOK, 256, 0, stream>>>(x, Ybuf, slotOf, gamma, beta, out);
  aux_kernel<<<1, 64, 0, stream>>>(P_sh, count, out + (size_t)T_TOK * DM);
}